// Round 12
// baseline (823.479 us; speedup 1.0000x reference)
//
#include <hip/hip_runtime.h>
#include <hip/hip_bf16.h>

// Problem constants
#define B_   64
#define T_   512
#define EMB_ 256
#define H_   256          // hidden per direction
#define L_   9
#define NROW (B_*T_)      // 32768
#define NG   2048         // both directions' gates

typedef __attribute__((ext_vector_type(4))) float f32x4;
typedef __attribute__((ext_vector_type(8))) short bf16x8;
typedef __attribute__((ext_vector_type(8))) int i32x8;

__device__ __forceinline__ float bf2f(unsigned short u) {
    union { unsigned int i; float f; } c; c.i = ((unsigned int)u) << 16; return c.f;
}
__device__ __forceinline__ unsigned int f2bf(float f) {
    union { unsigned int i; float f; } c; c.f = f;
    unsigned int i = c.i;
    return (i + 0x7FFFu + ((i >> 16) & 1u)) >> 16;
}
__device__ __forceinline__ float sigmf(float x) {
    return __builtin_amdgcn_rcpf(1.0f + __expf(-x));
}
__device__ __forceinline__ float tanh_fast(float x) {
    return 2.0f * __builtin_amdgcn_rcpf(1.0f + __expf(-2.0f * x)) - 1.0f;
}
// Raw block barrier ordering LDS only.
__device__ __forceinline__ void bar_lds() {
    asm volatile("s_waitcnt lgkmcnt(0)\n\ts_barrier" ::: "memory");
}

// ---------------------------------------------------------------------------
// bias[n] = b_ih + b_hh (both dirs)
// ---------------------------------------------------------------------------
__global__ void __launch_bounds__(256) bias_k(
    const float* __restrict__ bihf, const float* __restrict__ bhhf,
    const float* __restrict__ bihb, const float* __restrict__ bhhb,
    float* __restrict__ bias)
{
    int i = blockIdx.x * 256 + threadIdx.x;   // 0..2047
    if (i < 1024) bias[i] = bihf[i] + bhhf[i];
    else          bias[i] = bihb[i - 1024] + bhhb[i - 1024];
}

// ---------------------------------------------------------------------------
// Convert w_hh (both dirs) to fp8 e4m3, same row-major [1024][256] layout.
// ---------------------------------------------------------------------------
__global__ void __launch_bounds__(256) prep_w8(
    const float* __restrict__ wf, const float* __restrict__ wb,
    unsigned int* __restrict__ w8)
{
    int i = blockIdx.x * 256 + threadIdx.x;   // word index, 131072 total
    const float* src = (i < 65536) ? wf : wb;
    int j = (i & 65535) * 4;
    unsigned int pk = __builtin_amdgcn_cvt_pk_fp8_f32(src[j], src[j + 1], 0, false);
    pk = __builtin_amdgcn_cvt_pk_fp8_f32(src[j + 2], src[j + 3], pk, true);
    w8[i] = pk;
}

// ---------------------------------------------------------------------------
// xg GEMM via bf16 MFMA (unchanged from R8 — verified)
// ---------------------------------------------------------------------------
#define XBK 128
__global__ void __launch_bounds__(256, 2) xg_gemm_mfma(
    const float* __restrict__ emb, const int* __restrict__ ids,
    const float* __restrict__ w_f, const float* __restrict__ w_b,
    const float* __restrict__ bias, unsigned short* __restrict__ xg)
{
    __shared__ unsigned short A_lds[128][XBK + 8];
    __shared__ unsigned short B_lds[128][XBK + 8];
    __shared__ int rowtok[128];

    const int tid = threadIdx.x;
    const int row0 = blockIdx.x * 128;
    const int col0 = blockIdx.y * 128;
    const int w  = tid >> 6;             // wave 0..3
    const int wr = w >> 1, wc = w & 1;   // 64x64 subtile coords
    const int l  = tid & 63;
    const int l15 = l & 15, lq = l >> 4;

    if (tid < 128) rowtok[tid] = ids[row0 + tid];
    __syncthreads();

    f32x4 acc[4][4];
#pragma unroll
    for (int mt = 0; mt < 4; ++mt)
#pragma unroll
        for (int nt = 0; nt < 4; ++nt)
            acc[mt][nt] = (f32x4){0.f, 0.f, 0.f, 0.f};

    for (int kh = 0; kh < 2; ++kh) {
#pragma unroll
        for (int i = 0; i < 16; ++i) {
            int c = tid + i * 256;            // 0..4095
            int r = c >> 5, k4 = (c & 31) * 4;
            const float* src = emb + (size_t)rowtok[r] * EMB_ + kh * XBK + k4;
            float4 v = *(const float4*)src;
            ushort4 o;
            o.x = (unsigned short)f2bf(v.x); o.y = (unsigned short)f2bf(v.y);
            o.z = (unsigned short)f2bf(v.z); o.w = (unsigned short)f2bf(v.w);
            *(ushort4*)&A_lds[r][k4] = o;
        }
#pragma unroll
        for (int i = 0; i < 16; ++i) {
            int c = tid + i * 256;
            int r = c >> 5, k4 = (c & 31) * 4;
            int n = col0 + r;
            const float* wrow = (n < 1024) ? (w_f + (size_t)n * EMB_)
                                           : (w_b + (size_t)(n - 1024) * EMB_);
            float4 v = *(const float4*)(wrow + kh * XBK + k4);
            ushort4 o;
            o.x = (unsigned short)f2bf(v.x); o.y = (unsigned short)f2bf(v.y);
            o.z = (unsigned short)f2bf(v.z); o.w = (unsigned short)f2bf(v.w);
            *(ushort4*)&B_lds[r][k4] = o;
        }
        __syncthreads();

#pragma unroll
        for (int kt = 0; kt < 4; ++kt) {
            bf16x8 a[4], b[4];
#pragma unroll
            for (int mt = 0; mt < 4; ++mt)
                a[mt] = *(const bf16x8*)&A_lds[wr * 64 + mt * 16 + l15][kt * 32 + lq * 8];
#pragma unroll
            for (int nt = 0; nt < 4; ++nt)
                b[nt] = *(const bf16x8*)&B_lds[wc * 64 + nt * 16 + l15][kt * 32 + lq * 8];
#pragma unroll
            for (int mt = 0; mt < 4; ++mt)
#pragma unroll
                for (int nt = 0; nt < 4; ++nt)
                    acc[mt][nt] = __builtin_amdgcn_mfma_f32_16x16x32_bf16(
                        a[mt], b[nt], acc[mt][nt], 0, 0, 0);
        }
        __syncthreads();
    }

    float bv[4];
#pragma unroll
    for (int nt = 0; nt < 4; ++nt)
        bv[nt] = bias[col0 + wc * 64 + nt * 16 + l15];
#pragma unroll
    for (int mt = 0; mt < 4; ++mt)
#pragma unroll
        for (int r = 0; r < 4; ++r) {
            size_t row = (size_t)row0 + wr * 64 + mt * 16 + lq * 4 + r;
#pragma unroll
            for (int nt = 0; nt < 4; ++nt) {
                int col = col0 + wc * 64 + nt * 16 + l15;
                xg[row * NG + col] = (unsigned short)f2bf(acc[mt][nt][r] + bv[nt]);
            }
        }
}

// ---------------------------------------------------------------------------
// Fused LSTM — R9 VERSION VERBATIM (two barriers, single hbuf; verified,
// 429 us). The single-barrier double-buffer variant will be re-tried in
// isolation after the NaN source is identified.
// ---------------------------------------------------------------------------
__global__ void __launch_bounds__(512, 1) lstm_fused(
    const unsigned short* __restrict__ xg,
    const unsigned long long* __restrict__ w8,   // fp8 [2][1024][256] as u64
    unsigned short* __restrict__ h_hist)         // bf16 [2*64][512][256]
{
    const int bid = blockIdx.x;          // 0..63
    const int dir = bid >> 5;
    const int bbase = (bid & 31) * 2;    // 2 batches per block
    const int tid = threadIdx.x;
    const int w = tid >> 6;              // wave 0..7: j-slice [w*32, w*32+32)
    const int l = tid & 63;
    const int l15 = l & 15, lq = l >> 4;

    __shared__ unsigned long long hbuf[16 * 33];   // fp8 h, rows 2..15 stay 0
    __shared__ float pg[8][4][2][32];              // [wave][gate][b][j-local]

    for (int i = tid; i < 16 * 33; i += 512) hbuf[i] = 0ull;

    // Stationary fp8 B fragments for MX K=128:
    // row n = g*256 + w*32 + nt*16 + l15 ; bytes k = half*128 + lq*32 + e
    i32x8 bfrag[4][2][2];
    const unsigned long long* wbp = w8 + (size_t)dir * 32768;
#pragma unroll
    for (int g = 0; g < 4; ++g)
#pragma unroll
        for (int nt = 0; nt < 2; ++nt) {
            int row = g * 256 + w * 32 + nt * 16 + l15;
#pragma unroll
            for (int half = 0; half < 2; ++half) {
                union { unsigned long long u[4]; i32x8 v; } t;
#pragma unroll
                for (int q = 0; q < 4; ++q)
                    t.u[q] = wbp[row * 32 + half * 16 + lq * 4 + q];
                bfrag[g][nt][half] = t.v;
            }
        }

    // Per-thread h ownership (update phase): b-local = l>>5, j = w*32 + (l&31)
    const int bl = l >> 5;
    const int jl = l & 31;
    const int j  = w * 32 + jl;
    const int bg = bbase + bl;           // batch within dir
    float cst = 0.0f;
    const int sc1 = 0x7F7F7F7F;          // e8m0 scales, all 1.0

    // xg prefetch (4 gates for this thread's (bg, j))
    unsigned short xq[4];
    {
        int t0 = dir ? (T_ - 1) : 0;
        const unsigned short* xp = xg + ((size_t)bg * T_ + t0) * NG + dir * 1024 + j;
#pragma unroll
        for (int g = 0; g < 4; ++g) xq[g] = xp[g * 256];
    }
    __syncthreads();   // hbuf zeros visible

    for (int s = 0; s < T_; ++s) {
        const int t = dir ? (T_ - 1 - s) : s;

        // A fragments: h(s-1) fp8 from LDS, m = l15, k = half*128 + lq*32 + e
        i32x8 af0, af1;
        {
            union { unsigned long long u[4]; i32x8 v; } t0, t1;
#pragma unroll
            for (int q = 0; q < 4; ++q) {
                t0.u[q] = hbuf[l15 * 33 + lq * 4 + q];
                t1.u[q] = hbuf[l15 * 33 + 16 + lq * 4 + q];
            }
            af0 = t0.v; af1 = t1.v;
        }

        // MX MFMA: 16 per wave (4 gates x 2 n-tiles x 2 K-halves)
        f32x4 acc[4][2];
#pragma unroll
        for (int g = 0; g < 4; ++g)
#pragma unroll
            for (int nt = 0; nt < 2; ++nt)
                acc[g][nt] = (f32x4){0.f, 0.f, 0.f, 0.f};
#pragma unroll
        for (int g = 0; g < 4; ++g)
#pragma unroll
            for (int nt = 0; nt < 2; ++nt) {
                acc[g][nt] = __builtin_amdgcn_mfma_scale_f32_16x16x128_f8f6f4(
                    af0, bfrag[g][nt][0], acc[g][nt], 0, 0, 0, sc1, 0, sc1);
                acc[g][nt] = __builtin_amdgcn_mfma_scale_f32_16x16x128_f8f6f4(
                    af1, bfrag[g][nt][1], acc[g][nt], 0, 0, 0, sc1, 0, sc1);
            }

        // Redistribute gates via wave-private LDS (C/D row = lq*4+r -> rows
        // 0,1 live in lanes lq==0). Per-wave DS ops are in-order.
        if (lq == 0) {
#pragma unroll
            for (int g = 0; g < 4; ++g)
#pragma unroll
                for (int nt = 0; nt < 2; ++nt) {
                    pg[w][g][0][nt * 16 + l15] = acc[g][nt][0];
                    pg[w][g][1][nt * 16 + l15] = acc[g][nt][1];
                }
        }
        float gi = pg[w][0][bl][jl] + bf2f(xq[0]);
        float gf = pg[w][1][bl][jl] + bf2f(xq[1]);
        float gg = pg[w][2][bl][jl] + bf2f(xq[2]);
        float go = pg[w][3][bl][jl] + bf2f(xq[3]);

        // prefetch next step's xg (latency hidden under update + barriers)
        {
            int sn = (s + 1 < T_) ? (s + 1) : s;
            int tn = dir ? (T_ - 1 - sn) : sn;
            const unsigned short* xp = xg + ((size_t)bg * T_ + tn) * NG + dir * 1024 + j;
#pragma unroll
            for (int g = 0; g < 4; ++g) xq[g] = xp[g * 256];
        }

        // cell update: exactly one h per lane
        float c = sigmf(gf) * cst + sigmf(gi) * tanh_fast(gg);
        cst = c;
        float h = sigmf(go) * tanh_fast(c);

        // global bf16 history store (async, no drain needed)
        h_hist[((size_t)(dir * 64 + bg) * T_ + t) * 256 + j] =
            (unsigned short)f2bf(h);

        bar_lds();   // all waves done reading hbuf (af) before overwrite
        unsigned int p8 = __builtin_amdgcn_cvt_pk_fp8_f32(h, h, 0, false);
        ((unsigned char*)hbuf)[bl * 264 + j] = (unsigned char)(p8 & 0xffu);
        bar_lds();   // hbuf writes visible before next step's af reads
    }
}

// ---------------------------------------------------------------------------
// Emissions: 512 threads, 8 rows/block, w_cls staged in LDS once per block.
// ---------------------------------------------------------------------------
__global__ void __launch_bounds__(512) emis_k(
    const unsigned short* __restrict__ h_hist, const float* __restrict__ w_cls,
    const float* __restrict__ b_cls, float* __restrict__ em)
{
    __shared__ float wlds[L_ * 512];
    int tid = threadIdx.x;
    for (int i = tid; i < L_ * 512; i += 512) wlds[i] = w_cls[i];
    __syncthreads();

    int wid = tid >> 6, lane = tid & 63;
    size_t row = (size_t)blockIdx.x * 8 + wid;       // b*T + t
    const unsigned short* hf = h_hist + row * 256;
    const unsigned short* hb = h_hist + (size_t)64 * 512 * 256 + row * 256;
    ushort4 u0 = *(const ushort4*)(hf + 4 * lane);
    ushort4 u1 = *(const ushort4*)(hb + 4 * lane);
    float a0x = bf2f(u0.x), a0y = bf2f(u0.y), a0z = bf2f(u0.z), a0w = bf2f(u0.w);
    float a1x = bf2f(u1.x), a1y = bf2f(u1.y), a1z = bf2f(u1.z), a1w = bf2f(u1.w);
#pragma unroll
    for (int l = 0; l < L_; ++l) {
        const float* wr = &wlds[l * 512];
        float4 w0 = *(const float4*)(wr + 4 * lane);
        float4 w1 = *(const float4*)(wr + 256 + 4 * lane);
        float d = a0x * w0.x + a0y * w0.y + a0z * w0.z + a0w * w0.w
                + a1x * w1.x + a1y * w1.y + a1z * w1.z + a1w * w1.w;
#pragma unroll
        for (int off = 32; off; off >>= 1) d += __shfl_down(d, off);
        if (lane == 0) em[row * L_ + l] = d + b_cls[l];
    }
}

// ---------------------------------------------------------------------------
// CRF NLL: R9's verified LDS-alpha structure + register prefetch of the
// next step's emissions row and mask (load-scheduling only; sync unchanged).
// ---------------------------------------------------------------------------
__global__ void __launch_bounds__(64) crf_k(
    const float* __restrict__ em, const int* __restrict__ labels,
    const int* __restrict__ mask, const float* __restrict__ trans,
    const float* __restrict__ startv, const float* __restrict__ endv,
    float* __restrict__ out)
{
    int b = blockIdx.x, lane = threadIdx.x;
    const float* emb_ = em + (size_t)b * T_ * L_;
    const int* lab = labels + (size_t)b * T_;
    const int* msk = mask + (size_t)b * T_;
    __shared__ float alpha[L_];
    __shared__ float trs[81];
    for (int i = lane; i < 81; i += 64) trs[i] = trans[i];
    __syncthreads();

    // numerator (lane-parallel over t) — R9 verbatim
    float np = 0.0f;
    for (int t = 1 + lane; t < T_; t += 64)
        if (msk[t]) np += trs[lab[t - 1] * L_ + lab[t]] + emb_[(size_t)t * L_ + lab[t]];
    int mc = 0;
    for (int t = lane; t < T_; t += 64) mc += (msk[t] != 0);
#pragma unroll
    for (int off = 32; off; off >>= 1) {
        np += __shfl_down(np, off);
        mc += __shfl_down(mc, off);
    }
    float num = 0.0f;
    if (lane == 0) {
        int last = mc - 1;
        num = np + startv[lab[0]] + emb_[lab[0]] + endv[lab[last]];
    }

    // forward algorithm — R9 structure, with em/mask prefetched 1 step ahead
    int lane9 = (lane < L_) ? lane : 0;
    if (lane < L_) alpha[lane] = startv[lane] + emb_[lane];
    __syncthreads();

    float emt = emb_[L_ + lane9];    // prefetch t = 1
    int mk = msk[1];
    for (int t = 1; t < T_; ++t) {
        float em_c = emt;
        int mk_c = mk;
        if (t + 1 < T_) {            // prefetch t+1 (hides L2 latency)
            emt = emb_[(size_t)(t + 1) * L_ + lane9];
            mk = msk[t + 1];
        }
        float na = 0.0f;
        if (lane < L_) {
            float m = -1e30f;
#pragma unroll
            for (int i = 0; i < L_; ++i) m = fmaxf(m, alpha[i] + trs[i * L_ + lane]);
            float s = 0.0f;
#pragma unroll
            for (int i = 0; i < L_; ++i) s += __expf(alpha[i] + trs[i * L_ + lane] - m);
            na = m + __logf(s) + em_c;
            if (!mk_c) na = alpha[lane];
        }
        __syncthreads();
        if (lane < L_) alpha[lane] = na;
        __syncthreads();
    }
    float v = (lane < L_) ? alpha[lane] + endv[lane] : -1e30f;
    float m = v;
#pragma unroll
    for (int off = 32; off; off >>= 1) m = fmaxf(m, __shfl_xor(m, off));
    float s = (lane < L_) ? __expf(v - m) : 0.0f;
#pragma unroll
    for (int off = 32; off; off >>= 1) s += __shfl_xor(s, off);
    if (lane == 0) {
        float logZ = m + __logf(s);
        atomicAdd(out, (logZ - num) / (float)B_);
    }
}

__global__ void zero_out_k(float* out) { out[0] = 0.0f; }
__global__ void ws_fail_k(float* out, float v) { out[0] = v; }

// ---------------------------------------------------------------------------
extern "C" void kernel_launch(void* const* d_in, const int* in_sizes, int n_in,
                              void* d_out, int out_size, void* d_ws, size_t ws_size,
                              hipStream_t stream)
{
    const int*   ids    = (const int*)  d_in[0];
    const int*   amask  = (const int*)  d_in[1];
    const int*   labels = (const int*)  d_in[2];
    const float* emb    = (const float*)d_in[3];
    const float* w_ih_f = (const float*)d_in[4];
    const float* w_hh_f = (const float*)d_in[5];
    const float* b_ih_f = (const float*)d_in[6];
    const float* b_hh_f = (const float*)d_in[7];
    const float* w_ih_b = (const float*)d_in[8];
    const float* w_hh_b = (const float*)d_in[9];
    const float* b_ih_b = (const float*)d_in[10];
    const float* b_hh_b = (const float*)d_in[11];
    const float* w_cls  = (const float*)d_in[12];
    const float* b_cls  = (const float*)d_in[13];
    const float* trans  = (const float*)d_in[14];
    const float* startv = (const float*)d_in[15];
    const float* endv   = (const float*)d_in[16];
    float* out = (float*)d_out;

    // workspace layout
    size_t o_xg   = 0;                                   // bf16 xg: 128 MB
    size_t o_bias = o_xg + (size_t)NROW * NG * 2;
    size_t o_w8   = o_bias + 2048 * 4;                   // fp8 weights: 512 KB
    size_t o_hh   = o_w8 + (size_t)2 * 1024 * 256;       // h_hist: 32 MB
    size_t o_em   = o_hh + (size_t)2 * B_ * T_ * H_ * 2;
    size_t total  = o_em + (size_t)NROW * L_ * 4;

    if (ws_size < total) {
        ws_fail_k<<<1, 1, 0, stream>>>(out, -1.0e8f - (float)(ws_size >> 20));
        return;
    }

    unsigned short* xg       = (unsigned short*)((char*)d_ws + o_xg);
    float* bias              = (float*)((char*)d_ws + o_bias);
    unsigned int* w8         = (unsigned int*)((char*)d_ws + o_w8);
    unsigned short* h_hist   = (unsigned short*)((char*)d_ws + o_hh);
    float* em                = (float*)((char*)d_ws + o_em);

    bias_k<<<8, 256, 0, stream>>>(b_ih_f, b_hh_f, b_ih_b, b_hh_b, bias);
    prep_w8<<<512, 256, 0, stream>>>(w_hh_f, w_hh_b, w8);
    xg_gemm_mfma<<<dim3(NROW / 128, NG / 128), 256, 0, stream>>>(
        emb, ids, w_ih_f, w_ih_b, bias, xg);
    lstm_fused<<<64, 512, 0, stream>>>(xg, (const unsigned long long*)w8, h_hist);
    emis_k<<<NROW / 8, 512, 0, stream>>>(h_hist, w_cls, b_cls, em);
    zero_out_k<<<1, 1, 0, stream>>>(out);
    crf_k<<<B_, 64, 0, stream>>>(em, labels, amask, trans, startv, endv, out);
}

// Round 15
// 696.142 us; speedup vs baseline: 1.1829x; 1.1829x over previous
//
#include <hip/hip_runtime.h>
#include <hip/hip_bf16.h>

// Problem constants
#define B_   64
#define T_   512
#define EMB_ 256
#define H_   256          // hidden per direction
#define L_   9
#define NROW (B_*T_)      // 32768
#define NG   2048         // both directions' gates

typedef __attribute__((ext_vector_type(4))) float f32x4;
typedef __attribute__((ext_vector_type(8))) short bf16x8;
typedef __attribute__((ext_vector_type(8))) int i32x8;

__device__ __forceinline__ float bf2f(unsigned short u) {
    union { unsigned int i; float f; } c; c.i = ((unsigned int)u) << 16; return c.f;
}
__device__ __forceinline__ unsigned int f2bf(float f) {
    union { unsigned int i; float f; } c; c.f = f;
    unsigned int i = c.i;
    return (i + 0x7FFFu + ((i >> 16) & 1u)) >> 16;
}
__device__ __forceinline__ float sigmf(float x) {
    return __builtin_amdgcn_rcpf(1.0f + __expf(-x));
}
__device__ __forceinline__ float tanh_fast(float x) {
    return 2.0f * __builtin_amdgcn_rcpf(1.0f + __expf(-2.0f * x)) - 1.0f;
}
// Raw block barrier ordering LDS only.
__device__ __forceinline__ void bar_lds() {
    asm volatile("s_waitcnt lgkmcnt(0)\n\ts_barrier" ::: "memory");
}

// ---------------------------------------------------------------------------
// Convert embedding table fp32 -> bf16 (8000 blocks x 256 thr x 4 elems)
// ---------------------------------------------------------------------------
__global__ void __launch_bounds__(256) conv_emb(
    const float* __restrict__ emb, unsigned short* __restrict__ embb)
{
    size_t i = ((size_t)blockIdx.x * 256 + threadIdx.x) * 4;
    float4 v = *(const float4*)(emb + i);
    ushort4 o;
    o.x = (unsigned short)f2bf(v.x); o.y = (unsigned short)f2bf(v.y);
    o.z = (unsigned short)f2bf(v.z); o.w = (unsigned short)f2bf(v.w);
    *(ushort4*)(embb + i) = o;
}

// ---------------------------------------------------------------------------
// Fused prep: w_ih -> bf16 [2048][256] (blocks 0..511),
//             w_hh -> fp8 e4m3 (blocks 512..1023),
//             bias = b_ih + b_hh (blocks 1024..1031)
// ---------------------------------------------------------------------------
__global__ void __launch_bounds__(256) prep_misc(
    const float* __restrict__ w_ih_f, const float* __restrict__ w_ih_b,
    const float* __restrict__ w_hh_f, const float* __restrict__ w_hh_b,
    const float* __restrict__ bihf, const float* __restrict__ bhhf,
    const float* __restrict__ bihb, const float* __restrict__ bhhb,
    unsigned short* __restrict__ wihb, unsigned int* __restrict__ w8,
    float* __restrict__ bias)
{
    int bid = blockIdx.x, tid = threadIdx.x;
    if (bid < 512) {
        int idx = bid * 256 + tid;            // 0..131071, 4 floats each
        int j = idx * 4;
        const float* src = (idx < 65536) ? (w_ih_f + j) : (w_ih_b + (j - 262144));
        float4 v = *(const float4*)src;
        ushort4 o;
        o.x = (unsigned short)f2bf(v.x); o.y = (unsigned short)f2bf(v.y);
        o.z = (unsigned short)f2bf(v.z); o.w = (unsigned short)f2bf(v.w);
        *(ushort4*)(wihb + j) = o;
    } else if (bid < 1024) {
        int i = (bid - 512) * 256 + tid;      // word index, 131072 total
        const float* src = (i < 65536) ? w_hh_f : w_hh_b;
        int j = (i & 65535) * 4;
        unsigned int pk = __builtin_amdgcn_cvt_pk_fp8_f32(src[j], src[j + 1], 0, false);
        pk = __builtin_amdgcn_cvt_pk_fp8_f32(src[j + 2], src[j + 3], pk, true);
        w8[i] = pk;
    } else {
        int i = (bid - 1024) * 256 + tid;     // 0..2047
        if (i < 1024) bias[i] = bihf[i] + bhhf[i];
        else          bias[i] = bihb[i - 1024] + bhhb[i - 1024];
    }
}

// ---------------------------------------------------------------------------
// xg GEMM via bf16 MFMA, v2 FIXED: 128x128 bf16 tile = 2048 granules of 16 B
// -> 8 staging iterations (R13 bug: 4 iters staged only K<64; K>=64 was
// uninitialized LDS -> NaN). MFMA loop + epilogue identical to verified R8.
// ---------------------------------------------------------------------------
#define XBK 128
__global__ void __launch_bounds__(256, 2) xg_gemm_mfma(
    const unsigned short* __restrict__ embb, const int* __restrict__ ids,
    const unsigned short* __restrict__ wihb,
    const float* __restrict__ bias, unsigned short* __restrict__ xg)
{
    __shared__ unsigned short A_lds[128][XBK + 8];
    __shared__ unsigned short B_lds[128][XBK + 8];
    __shared__ int rowtok[128];

    const int tid = threadIdx.x;
    const int row0 = blockIdx.x * 128;
    const int col0 = blockIdx.y * 128;
    const int w  = tid >> 6;             // wave 0..3
    const int wr = w >> 1, wc = w & 1;   // 64x64 subtile coords
    const int l  = tid & 63;
    const int l15 = l & 15, lq = l >> 4;

    if (tid < 128) rowtok[tid] = ids[row0 + tid];
    __syncthreads();

    f32x4 acc[4][4];
#pragma unroll
    for (int mt = 0; mt < 4; ++mt)
#pragma unroll
        for (int nt = 0; nt < 4; ++nt)
            acc[mt][nt] = (f32x4){0.f, 0.f, 0.f, 0.f};

    for (int kh = 0; kh < 2; ++kh) {
        // stage A (gathered bf16 emb rows): 2048 granules of 16 B, 8 iters
#pragma unroll
        for (int i = 0; i < 8; ++i) {
            int c = tid + i * 256;            // granule id 0..2047
            int r = c >> 4, k8 = (c & 15) * 8;
            uint4 v = *(const uint4*)(embb + (size_t)rowtok[r] * EMB_ + kh * XBK + k8);
            *(uint4*)&A_lds[r][k8] = v;
        }
        // stage B (bf16 gate-weight rows): 2048 granules of 16 B, 8 iters
#pragma unroll
        for (int i = 0; i < 8; ++i) {
            int c = tid + i * 256;
            int r = c >> 4, k8 = (c & 15) * 8;
            uint4 v = *(const uint4*)(wihb + (size_t)(col0 + r) * EMB_ + kh * XBK + k8);
            *(uint4*)&B_lds[r][k8] = v;
        }
        __syncthreads();

#pragma unroll
        for (int kt = 0; kt < 4; ++kt) {
            bf16x8 a[4], b[4];
#pragma unroll
            for (int mt = 0; mt < 4; ++mt)
                a[mt] = *(const bf16x8*)&A_lds[wr * 64 + mt * 16 + l15][kt * 32 + lq * 8];
#pragma unroll
            for (int nt = 0; nt < 4; ++nt)
                b[nt] = *(const bf16x8*)&B_lds[wc * 64 + nt * 16 + l15][kt * 32 + lq * 8];
#pragma unroll
            for (int mt = 0; mt < 4; ++mt)
#pragma unroll
                for (int nt = 0; nt < 4; ++nt)
                    acc[mt][nt] = __builtin_amdgcn_mfma_f32_16x16x32_bf16(
                        a[mt], b[nt], acc[mt][nt], 0, 0, 0);
        }
        __syncthreads();
    }

    float bv[4];
#pragma unroll
    for (int nt = 0; nt < 4; ++nt)
        bv[nt] = bias[col0 + wc * 64 + nt * 16 + l15];
#pragma unroll
    for (int mt = 0; mt < 4; ++mt)
#pragma unroll
        for (int r = 0; r < 4; ++r) {
            size_t row = (size_t)row0 + wr * 64 + mt * 16 + lq * 4 + r;
#pragma unroll
            for (int nt = 0; nt < 4; ++nt) {
                int col = col0 + wc * 64 + nt * 16 + l15;
                xg[row * NG + col] = (unsigned short)f2bf(acc[mt][nt][r] + bv[nt]);
            }
        }
}

// ---------------------------------------------------------------------------
// Fused LSTM — R11 VERSION VERBATIM (two barriers, single hbuf; verified at
// 430 us).
// ---------------------------------------------------------------------------
__global__ void __launch_bounds__(512, 1) lstm_fused(
    const unsigned short* __restrict__ xg,
    const unsigned long long* __restrict__ w8,   // fp8 [2][1024][256] as u64
    unsigned short* __restrict__ h_hist)         // bf16 [2*64][512][256]
{
    const int bid = blockIdx.x;          // 0..63
    const int dir = bid >> 5;
    const int bbase = (bid & 31) * 2;    // 2 batches per block
    const int tid = threadIdx.x;
    const int w = tid >> 6;              // wave 0..7: j-slice [w*32, w*32+32)
    const int l = tid & 63;
    const int l15 = l & 15, lq = l >> 4;

    __shared__ unsigned long long hbuf[16 * 33];   // fp8 h, rows 2..15 stay 0
    __shared__ float pg[8][4][2][32];              // [wave][gate][b][j-local]

    for (int i = tid; i < 16 * 33; i += 512) hbuf[i] = 0ull;

    // Stationary fp8 B fragments for MX K=128:
    // row n = g*256 + w*32 + nt*16 + l15 ; bytes k = half*128 + lq*32 + e
    i32x8 bfrag[4][2][2];
    const unsigned long long* wbp = w8 + (size_t)dir * 32768;
#pragma unroll
    for (int g = 0; g < 4; ++g)
#pragma unroll
        for (int nt = 0; nt < 2; ++nt) {
            int row = g * 256 + w * 32 + nt * 16 + l15;
#pragma unroll
            for (int half = 0; half < 2; ++half) {
                union { unsigned long long u[4]; i32x8 v; } t;
#pragma unroll
                for (int q = 0; q < 4; ++q)
                    t.u[q] = wbp[row * 32 + half * 16 + lq * 4 + q];
                bfrag[g][nt][half] = t.v;
            }
        }

    // Per-thread h ownership (update phase): b-local = l>>5, j = w*32 + (l&31)
    const int bl = l >> 5;
    const int jl = l & 31;
    const int j  = w * 32 + jl;
    const int bg = bbase + bl;           // batch within dir
    float cst = 0.0f;
    const int sc1 = 0x7F7F7F7F;          // e8m0 scales, all 1.0

    // xg prefetch (4 gates for this thread's (bg, j))
    unsigned short xq[4];
    {
        int t0 = dir ? (T_ - 1) : 0;
        const unsigned short* xp = xg + ((size_t)bg * T_ + t0) * NG + dir * 1024 + j;
#pragma unroll
        for (int g = 0; g < 4; ++g) xq[g] = xp[g * 256];
    }
    __syncthreads();   // hbuf zeros visible

    for (int s = 0; s < T_; ++s) {
        const int t = dir ? (T_ - 1 - s) : s;

        // A fragments: h(s-1) fp8 from LDS, m = l15, k = half*128 + lq*32 + e
        i32x8 af0, af1;
        {
            union { unsigned long long u[4]; i32x8 v; } t0, t1;
#pragma unroll
            for (int q = 0; q < 4; ++q) {
                t0.u[q] = hbuf[l15 * 33 + lq * 4 + q];
                t1.u[q] = hbuf[l15 * 33 + 16 + lq * 4 + q];
            }
            af0 = t0.v; af1 = t1.v;
        }

        // MX MFMA: 16 per wave (4 gates x 2 n-tiles x 2 K-halves)
        f32x4 acc[4][2];
#pragma unroll
        for (int g = 0; g < 4; ++g)
#pragma unroll
            for (int nt = 0; nt < 2; ++nt)
                acc[g][nt] = (f32x4){0.f, 0.f, 0.f, 0.f};
#pragma unroll
        for (int g = 0; g < 4; ++g)
#pragma unroll
            for (int nt = 0; nt < 2; ++nt) {
                acc[g][nt] = __builtin_amdgcn_mfma_scale_f32_16x16x128_f8f6f4(
                    af0, bfrag[g][nt][0], acc[g][nt], 0, 0, 0, sc1, 0, sc1);
                acc[g][nt] = __builtin_amdgcn_mfma_scale_f32_16x16x128_f8f6f4(
                    af1, bfrag[g][nt][1], acc[g][nt], 0, 0, 0, sc1, 0, sc1);
            }

        // Redistribute gates via wave-private LDS (C/D row = lq*4+r -> rows
        // 0,1 live in lanes lq==0). Per-wave DS ops are in-order.
        if (lq == 0) {
#pragma unroll
            for (int g = 0; g < 4; ++g)
#pragma unroll
                for (int nt = 0; nt < 2; ++nt) {
                    pg[w][g][0][nt * 16 + l15] = acc[g][nt][0];
                    pg[w][g][1][nt * 16 + l15] = acc[g][nt][1];
                }
        }
        float gi = pg[w][0][bl][jl] + bf2f(xq[0]);
        float gf = pg[w][1][bl][jl] + bf2f(xq[1]);
        float gg = pg[w][2][bl][jl] + bf2f(xq[2]);
        float go = pg[w][3][bl][jl] + bf2f(xq[3]);

        // prefetch next step's xg (latency hidden under update + barriers)
        {
            int sn = (s + 1 < T_) ? (s + 1) : s;
            int tn = dir ? (T_ - 1 - sn) : sn;
            const unsigned short* xp = xg + ((size_t)bg * T_ + tn) * NG + dir * 1024 + j;
#pragma unroll
            for (int g = 0; g < 4; ++g) xq[g] = xp[g * 256];
        }

        // cell update: exactly one h per lane
        float c = sigmf(gf) * cst + sigmf(gi) * tanh_fast(gg);
        cst = c;
        float h = sigmf(go) * tanh_fast(c);

        // global bf16 history store (async, no drain needed)
        h_hist[((size_t)(dir * 64 + bg) * T_ + t) * 256 + j] =
            (unsigned short)f2bf(h);

        bar_lds();   // all waves done reading hbuf (af) before overwrite
        unsigned int p8 = __builtin_amdgcn_cvt_pk_fp8_f32(h, h, 0, false);
        ((unsigned char*)hbuf)[bl * 264 + j] = (unsigned char)(p8 & 0xffu);
        bar_lds();   // hbuf writes visible before next step's af reads
    }
}

// ---------------------------------------------------------------------------
// Emissions: 512 threads, 8 rows/block, w_cls staged in LDS once per block.
// (R11 verbatim — verified)
// ---------------------------------------------------------------------------
__global__ void __launch_bounds__(512) emis_k(
    const unsigned short* __restrict__ h_hist, const float* __restrict__ w_cls,
    const float* __restrict__ b_cls, float* __restrict__ em)
{
    __shared__ float wlds[L_ * 512];
    int tid = threadIdx.x;
    for (int i = tid; i < L_ * 512; i += 512) wlds[i] = w_cls[i];
    __syncthreads();

    int wid = tid >> 6, lane = tid & 63;
    size_t row = (size_t)blockIdx.x * 8 + wid;       // b*T + t
    const unsigned short* hf = h_hist + row * 256;
    const unsigned short* hb = h_hist + (size_t)64 * 512 * 256 + row * 256;
    ushort4 u0 = *(const ushort4*)(hf + 4 * lane);
    ushort4 u1 = *(const ushort4*)(hb + 4 * lane);
    float a0x = bf2f(u0.x), a0y = bf2f(u0.y), a0z = bf2f(u0.z), a0w = bf2f(u0.w);
    float a1x = bf2f(u1.x), a1y = bf2f(u1.y), a1z = bf2f(u1.z), a1w = bf2f(u1.w);
#pragma unroll
    for (int l = 0; l < L_; ++l) {
        const float* wr = &wlds[l * 512];
        float4 w0 = *(const float4*)(wr + 4 * lane);
        float4 w1 = *(const float4*)(wr + 256 + 4 * lane);
        float d = a0x * w0.x + a0y * w0.y + a0z * w0.z + a0w * w0.w
                + a1x * w1.x + a1y * w1.y + a1z * w1.z + a1w * w1.w;
#pragma unroll
        for (int off = 32; off; off >>= 1) d += __shfl_down(d, off);
        if (lane == 0) em[row * L_ + l] = d + b_cls[l];
    }
}

// ---------------------------------------------------------------------------
// CRF NLL (R11 verbatim — verified)
// ---------------------------------------------------------------------------
__global__ void __launch_bounds__(64) crf_k(
    const float* __restrict__ em, const int* __restrict__ labels,
    const int* __restrict__ mask, const float* __restrict__ trans,
    const float* __restrict__ startv, const float* __restrict__ endv,
    float* __restrict__ out)
{
    int b = blockIdx.x, lane = threadIdx.x;
    const float* emb_ = em + (size_t)b * T_ * L_;
    const int* lab = labels + (size_t)b * T_;
    const int* msk = mask + (size_t)b * T_;
    __shared__ float alpha[L_];
    __shared__ float trs[81];
    for (int i = lane; i < 81; i += 64) trs[i] = trans[i];
    __syncthreads();

    float np = 0.0f;
    for (int t = 1 + lane; t < T_; t += 64)
        if (msk[t]) np += trs[lab[t - 1] * L_ + lab[t]] + emb_[(size_t)t * L_ + lab[t]];
    int mc = 0;
    for (int t = lane; t < T_; t += 64) mc += (msk[t] != 0);
#pragma unroll
    for (int off = 32; off; off >>= 1) {
        np += __shfl_down(np, off);
        mc += __shfl_down(mc, off);
    }
    float num = 0.0f;
    if (lane == 0) {
        int last = mc - 1;
        num = np + startv[lab[0]] + emb_[lab[0]] + endv[lab[last]];
    }

    int lane9 = (lane < L_) ? lane : 0;
    if (lane < L_) alpha[lane] = startv[lane] + emb_[lane];
    __syncthreads();

    float emt = emb_[L_ + lane9];    // prefetch t = 1
    int mk = msk[1];
    for (int t = 1; t < T_; ++t) {
        float em_c = emt;
        int mk_c = mk;
        if (t + 1 < T_) {
            emt = emb_[(size_t)(t + 1) * L_ + lane9];
            mk = msk[t + 1];
        }
        float na = 0.0f;
        if (lane < L_) {
            float m = -1e30f;
#pragma unroll
            for (int i = 0; i < L_; ++i) m = fmaxf(m, alpha[i] + trs[i * L_ + lane]);
            float s = 0.0f;
#pragma unroll
            for (int i = 0; i < L_; ++i) s += __expf(alpha[i] + trs[i * L_ + lane] - m);
            na = m + __logf(s) + em_c;
            if (!mk_c) na = alpha[lane];
        }
        __syncthreads();
        if (lane < L_) alpha[lane] = na;
        __syncthreads();
    }
    float v = (lane < L_) ? alpha[lane] + endv[lane] : -1e30f;
    float m = v;
#pragma unroll
    for (int off = 32; off; off >>= 1) m = fmaxf(m, __shfl_xor(m, off));
    float s = (lane < L_) ? __expf(v - m) : 0.0f;
#pragma unroll
    for (int off = 32; off; off >>= 1) s += __shfl_xor(s, off);
    if (lane == 0) {
        float logZ = m + __logf(s);
        atomicAdd(out, (logZ - num) / (float)B_);
    }
}

__global__ void zero_out_k(float* out) { out[0] = 0.0f; }
__global__ void ws_fail_k(float* out, float v) { out[0] = v; }

// ---------------------------------------------------------------------------
extern "C" void kernel_launch(void* const* d_in, const int* in_sizes, int n_in,
                              void* d_out, int out_size, void* d_ws, size_t ws_size,
                              hipStream_t stream)
{
    const int*   ids    = (const int*)  d_in[0];
    const int*   amask  = (const int*)  d_in[1];
    const int*   labels = (const int*)  d_in[2];
    const float* emb    = (const float*)d_in[3];
    const float* w_ih_f = (const float*)d_in[4];
    const float* w_hh_f = (const float*)d_in[5];
    const float* b_ih_f = (const float*)d_in[6];
    const float* b_hh_f = (const float*)d_in[7];
    const float* w_ih_b = (const float*)d_in[8];
    const float* w_hh_b = (const float*)d_in[9];
    const float* b_ih_b = (const float*)d_in[10];
    const float* b_hh_b = (const float*)d_in[11];
    const float* w_cls  = (const float*)d_in[12];
    const float* b_cls  = (const float*)d_in[13];
    const float* trans  = (const float*)d_in[14];
    const float* startv = (const float*)d_in[15];
    const float* endv   = (const float*)d_in[16];
    float* out = (float*)d_out;

    // workspace layout (16B-aligned chunks)
    size_t o_xg   = 0;                                    // bf16 xg: 128 MB
    size_t o_bias = o_xg + (size_t)NROW * NG * 2;
    size_t o_w8   = o_bias + 2048 * 4;                    // fp8 weights: 512 KB
    size_t o_embb = o_w8 + (size_t)2 * 1024 * 256;        // bf16 emb: 15.6 MB
    size_t o_wihb = o_embb + (size_t)32000 * 256 * 2;     // bf16 w_ih: 1 MB
    size_t o_hh   = o_wihb + (size_t)2048 * 256 * 2;      // h_hist: 32 MB
    size_t o_em   = o_hh + (size_t)2 * B_ * T_ * H_ * 2;
    size_t total  = o_em + (size_t)NROW * L_ * 4;

    if (ws_size < total) {
        ws_fail_k<<<1, 1, 0, stream>>>(out, -1.0e8f - (float)(ws_size >> 20));
        return;
    }

    unsigned short* xg       = (unsigned short*)((char*)d_ws + o_xg);
    float* bias              = (float*)((char*)d_ws + o_bias);
    unsigned int* w8         = (unsigned int*)((char*)d_ws + o_w8);
    unsigned short* embb     = (unsigned short*)((char*)d_ws + o_embb);
    unsigned short* wihb     = (unsigned short*)((char*)d_ws + o_wihb);
    unsigned short* h_hist   = (unsigned short*)((char*)d_ws + o_hh);
    float* em                = (float*)((char*)d_ws + o_em);

    conv_emb<<<8000, 256, 0, stream>>>(emb, embb);
    prep_misc<<<1032, 256, 0, stream>>>(w_ih_f, w_ih_b, w_hh_f, w_hh_b,
                                        b_ih_f, b_hh_f, b_ih_b, b_hh_b,
                                        wihb, w8, bias);
    xg_gemm_mfma<<<dim3(NROW / 128, NG / 128), 256, 0, stream>>>(
        embb, ids, wihb, bias, xg);
    lstm_fused<<<64, 512, 0, stream>>>(xg, (const unsigned long long*)w8, h_hist);
    emis_k<<<NROW / 8, 512, 0, stream>>>(h_hist, w_cls, b_cls, em);
    zero_out_k<<<1, 1, 0, stream>>>(out);
    crf_k<<<B_, 64, 0, stream>>>(em, labels, amask, trans, startv, endv, out);
}

// Round 16
// 692.436 us; speedup vs baseline: 1.1892x; 1.0054x over previous
//
#include <hip/hip_runtime.h>
#include <hip/hip_bf16.h>

// Problem constants
#define B_   64
#define T_   512
#define EMB_ 256
#define H_   256          // hidden per direction
#define L_   9
#define NROW (B_*T_)      // 32768
#define NG   2048         // both directions' gates

typedef __attribute__((ext_vector_type(4))) float f32x4;
typedef __attribute__((ext_vector_type(8))) short bf16x8;
typedef __attribute__((ext_vector_type(8))) int i32x8;

__device__ __forceinline__ float bf2f(unsigned short u) {
    union { unsigned int i; float f; } c; c.i = ((unsigned int)u) << 16; return c.f;
}
__device__ __forceinline__ unsigned int f2bf(float f) {
    union { unsigned int i; float f; } c; c.f = f;
    unsigned int i = c.i;
    return (i + 0x7FFFu + ((i >> 16) & 1u)) >> 16;
}
__device__ __forceinline__ float sigmf(float x) {
    return __builtin_amdgcn_rcpf(1.0f + __expf(-x));
}
__device__ __forceinline__ float tanh_fast(float x) {
    return 2.0f * __builtin_amdgcn_rcpf(1.0f + __expf(-2.0f * x)) - 1.0f;
}
// Raw block barrier ordering LDS only.
__device__ __forceinline__ void bar_lds() {
    asm volatile("s_waitcnt lgkmcnt(0)\n\ts_barrier" ::: "memory");
}

// ---------------------------------------------------------------------------
// Fused prepass (merges R14's conv_emb + prep_misc; bodies verbatim):
//   blocks [0, 8000)      : emb fp32 -> bf16 (4 elems/thread)
//   blocks [8000, 8512)   : w_ih -> bf16 [2048][256]
//   blocks [8512, 9024)   : w_hh -> fp8 e4m3
//   blocks [9024, 9032)   : bias = b_ih + b_hh
// ---------------------------------------------------------------------------
__global__ void __launch_bounds__(256) prep_all(
    const float* __restrict__ emb, unsigned short* __restrict__ embb,
    const float* __restrict__ w_ih_f, const float* __restrict__ w_ih_b,
    const float* __restrict__ w_hh_f, const float* __restrict__ w_hh_b,
    const float* __restrict__ bihf, const float* __restrict__ bhhf,
    const float* __restrict__ bihb, const float* __restrict__ bhhb,
    unsigned short* __restrict__ wihb, unsigned int* __restrict__ w8,
    float* __restrict__ bias)
{
    int bid = blockIdx.x, tid = threadIdx.x;
    if (bid < 8000) {
        size_t i = ((size_t)bid * 256 + tid) * 4;
        float4 v = *(const float4*)(emb + i);
        ushort4 o;
        o.x = (unsigned short)f2bf(v.x); o.y = (unsigned short)f2bf(v.y);
        o.z = (unsigned short)f2bf(v.z); o.w = (unsigned short)f2bf(v.w);
        *(ushort4*)(embb + i) = o;
    } else if (bid < 8512) {
        int idx = (bid - 8000) * 256 + tid;   // 0..131071, 4 floats each
        int j = idx * 4;
        const float* src = (idx < 65536) ? (w_ih_f + j) : (w_ih_b + (j - 262144));
        float4 v = *(const float4*)src;
        ushort4 o;
        o.x = (unsigned short)f2bf(v.x); o.y = (unsigned short)f2bf(v.y);
        o.z = (unsigned short)f2bf(v.z); o.w = (unsigned short)f2bf(v.w);
        *(ushort4*)(wihb + j) = o;
    } else if (bid < 9024) {
        int i = (bid - 8512) * 256 + tid;     // word index, 131072 total
        const float* src = (i < 65536) ? w_hh_f : w_hh_b;
        int j = (i & 65535) * 4;
        unsigned int pk = __builtin_amdgcn_cvt_pk_fp8_f32(src[j], src[j + 1], 0, false);
        pk = __builtin_amdgcn_cvt_pk_fp8_f32(src[j + 2], src[j + 3], pk, true);
        w8[i] = pk;
    } else {
        int i = (bid - 9024) * 256 + tid;     // 0..2047
        if (i < 1024) bias[i] = bihf[i] + bhhf[i];
        else          bias[i] = bihb[i - 1024] + bhhb[i - 1024];
    }
}

// ---------------------------------------------------------------------------
// xg GEMM via bf16 MFMA (R14 verbatim — verified)
// ---------------------------------------------------------------------------
#define XBK 128
__global__ void __launch_bounds__(256, 2) xg_gemm_mfma(
    const unsigned short* __restrict__ embb, const int* __restrict__ ids,
    const unsigned short* __restrict__ wihb,
    const float* __restrict__ bias, unsigned short* __restrict__ xg)
{
    __shared__ unsigned short A_lds[128][XBK + 8];
    __shared__ unsigned short B_lds[128][XBK + 8];
    __shared__ int rowtok[128];

    const int tid = threadIdx.x;
    const int row0 = blockIdx.x * 128;
    const int col0 = blockIdx.y * 128;
    const int w  = tid >> 6;             // wave 0..3
    const int wr = w >> 1, wc = w & 1;   // 64x64 subtile coords
    const int l  = tid & 63;
    const int l15 = l & 15, lq = l >> 4;

    if (tid < 128) rowtok[tid] = ids[row0 + tid];
    __syncthreads();

    f32x4 acc[4][4];
#pragma unroll
    for (int mt = 0; mt < 4; ++mt)
#pragma unroll
        for (int nt = 0; nt < 4; ++nt)
            acc[mt][nt] = (f32x4){0.f, 0.f, 0.f, 0.f};

    for (int kh = 0; kh < 2; ++kh) {
        // stage A (gathered bf16 emb rows): 2048 granules of 16 B, 8 iters
#pragma unroll
        for (int i = 0; i < 8; ++i) {
            int c = tid + i * 256;            // granule id 0..2047
            int r = c >> 4, k8 = (c & 15) * 8;
            uint4 v = *(const uint4*)(embb + (size_t)rowtok[r] * EMB_ + kh * XBK + k8);
            *(uint4*)&A_lds[r][k8] = v;
        }
        // stage B (bf16 gate-weight rows): 2048 granules of 16 B, 8 iters
#pragma unroll
        for (int i = 0; i < 8; ++i) {
            int c = tid + i * 256;
            int r = c >> 4, k8 = (c & 15) * 8;
            uint4 v = *(const uint4*)(wihb + (size_t)(col0 + r) * EMB_ + kh * XBK + k8);
            *(uint4*)&B_lds[r][k8] = v;
        }
        __syncthreads();

#pragma unroll
        for (int kt = 0; kt < 4; ++kt) {
            bf16x8 a[4], b[4];
#pragma unroll
            for (int mt = 0; mt < 4; ++mt)
                a[mt] = *(const bf16x8*)&A_lds[wr * 64 + mt * 16 + l15][kt * 32 + lq * 8];
#pragma unroll
            for (int nt = 0; nt < 4; ++nt)
                b[nt] = *(const bf16x8*)&B_lds[wc * 64 + nt * 16 + l15][kt * 32 + lq * 8];
#pragma unroll
            for (int mt = 0; mt < 4; ++mt)
#pragma unroll
                for (int nt = 0; nt < 4; ++nt)
                    acc[mt][nt] = __builtin_amdgcn_mfma_f32_16x16x32_bf16(
                        a[mt], b[nt], acc[mt][nt], 0, 0, 0);
        }
        __syncthreads();
    }

    float bv[4];
#pragma unroll
    for (int nt = 0; nt < 4; ++nt)
        bv[nt] = bias[col0 + wc * 64 + nt * 16 + l15];
#pragma unroll
    for (int mt = 0; mt < 4; ++mt)
#pragma unroll
        for (int r = 0; r < 4; ++r) {
            size_t row = (size_t)row0 + wr * 64 + mt * 16 + lq * 4 + r;
#pragma unroll
            for (int nt = 0; nt < 4; ++nt) {
                int col = col0 + wc * 64 + nt * 16 + l15;
                xg[row * NG + col] = (unsigned short)f2bf(acc[mt][nt][r] + bv[nt]);
            }
        }
}

// ---------------------------------------------------------------------------
// Fused LSTM — R11/R14 VERSION VERBATIM (two barriers, single hbuf; verified
// at 430 us).
// ---------------------------------------------------------------------------
__global__ void __launch_bounds__(512, 1) lstm_fused(
    const unsigned short* __restrict__ xg,
    const unsigned long long* __restrict__ w8,   // fp8 [2][1024][256] as u64
    unsigned short* __restrict__ h_hist)         // bf16 [2*64][512][256]
{
    const int bid = blockIdx.x;          // 0..63
    const int dir = bid >> 5;
    const int bbase = (bid & 31) * 2;    // 2 batches per block
    const int tid = threadIdx.x;
    const int w = tid >> 6;              // wave 0..7: j-slice [w*32, w*32+32)
    const int l = tid & 63;
    const int l15 = l & 15, lq = l >> 4;

    __shared__ unsigned long long hbuf[16 * 33];   // fp8 h, rows 2..15 stay 0
    __shared__ float pg[8][4][2][32];              // [wave][gate][b][j-local]

    for (int i = tid; i < 16 * 33; i += 512) hbuf[i] = 0ull;

    // Stationary fp8 B fragments for MX K=128:
    // row n = g*256 + w*32 + nt*16 + l15 ; bytes k = half*128 + lq*32 + e
    i32x8 bfrag[4][2][2];
    const unsigned long long* wbp = w8 + (size_t)dir * 32768;
#pragma unroll
    for (int g = 0; g < 4; ++g)
#pragma unroll
        for (int nt = 0; nt < 2; ++nt) {
            int row = g * 256 + w * 32 + nt * 16 + l15;
#pragma unroll
            for (int half = 0; half < 2; ++half) {
                union { unsigned long long u[4]; i32x8 v; } t;
#pragma unroll
                for (int q = 0; q < 4; ++q)
                    t.u[q] = wbp[row * 32 + half * 16 + lq * 4 + q];
                bfrag[g][nt][half] = t.v;
            }
        }

    // Per-thread h ownership (update phase): b-local = l>>5, j = w*32 + (l&31)
    const int bl = l >> 5;
    const int jl = l & 31;
    const int j  = w * 32 + jl;
    const int bg = bbase + bl;           // batch within dir
    float cst = 0.0f;
    const int sc1 = 0x7F7F7F7F;          // e8m0 scales, all 1.0

    // xg prefetch (4 gates for this thread's (bg, j))
    unsigned short xq[4];
    {
        int t0 = dir ? (T_ - 1) : 0;
        const unsigned short* xp = xg + ((size_t)bg * T_ + t0) * NG + dir * 1024 + j;
#pragma unroll
        for (int g = 0; g < 4; ++g) xq[g] = xp[g * 256];
    }
    __syncthreads();   // hbuf zeros visible

    for (int s = 0; s < T_; ++s) {
        const int t = dir ? (T_ - 1 - s) : s;

        // A fragments: h(s-1) fp8 from LDS, m = l15, k = half*128 + lq*32 + e
        i32x8 af0, af1;
        {
            union { unsigned long long u[4]; i32x8 v; } t0, t1;
#pragma unroll
            for (int q = 0; q < 4; ++q) {
                t0.u[q] = hbuf[l15 * 33 + lq * 4 + q];
                t1.u[q] = hbuf[l15 * 33 + 16 + lq * 4 + q];
            }
            af0 = t0.v; af1 = t1.v;
        }

        // MX MFMA: 16 per wave (4 gates x 2 n-tiles x 2 K-halves)
        f32x4 acc[4][2];
#pragma unroll
        for (int g = 0; g < 4; ++g)
#pragma unroll
            for (int nt = 0; nt < 2; ++nt)
                acc[g][nt] = (f32x4){0.f, 0.f, 0.f, 0.f};
#pragma unroll
        for (int g = 0; g < 4; ++g)
#pragma unroll
            for (int nt = 0; nt < 2; ++nt) {
                acc[g][nt] = __builtin_amdgcn_mfma_scale_f32_16x16x128_f8f6f4(
                    af0, bfrag[g][nt][0], acc[g][nt], 0, 0, 0, sc1, 0, sc1);
                acc[g][nt] = __builtin_amdgcn_mfma_scale_f32_16x16x128_f8f6f4(
                    af1, bfrag[g][nt][1], acc[g][nt], 0, 0, 0, sc1, 0, sc1);
            }

        // Redistribute gates via wave-private LDS (C/D row = lq*4+r -> rows
        // 0,1 live in lanes lq==0). Per-wave DS ops are in-order.
        if (lq == 0) {
#pragma unroll
            for (int g = 0; g < 4; ++g)
#pragma unroll
                for (int nt = 0; nt < 2; ++nt) {
                    pg[w][g][0][nt * 16 + l15] = acc[g][nt][0];
                    pg[w][g][1][nt * 16 + l15] = acc[g][nt][1];
                }
        }
        float gi = pg[w][0][bl][jl] + bf2f(xq[0]);
        float gf = pg[w][1][bl][jl] + bf2f(xq[1]);
        float gg = pg[w][2][bl][jl] + bf2f(xq[2]);
        float go = pg[w][3][bl][jl] + bf2f(xq[3]);

        // prefetch next step's xg (latency hidden under update + barriers)
        {
            int sn = (s + 1 < T_) ? (s + 1) : s;
            int tn = dir ? (T_ - 1 - sn) : sn;
            const unsigned short* xp = xg + ((size_t)bg * T_ + tn) * NG + dir * 1024 + j;
#pragma unroll
            for (int g = 0; g < 4; ++g) xq[g] = xp[g * 256];
        }

        // cell update: exactly one h per lane
        float c = sigmf(gf) * cst + sigmf(gi) * tanh_fast(gg);
        cst = c;
        float h = sigmf(go) * tanh_fast(c);

        // global bf16 history store (async, no drain needed)
        h_hist[((size_t)(dir * 64 + bg) * T_ + t) * 256 + j] =
            (unsigned short)f2bf(h);

        bar_lds();   // all waves done reading hbuf (af) before overwrite
        unsigned int p8 = __builtin_amdgcn_cvt_pk_fp8_f32(h, h, 0, false);
        ((unsigned char*)hbuf)[bl * 264 + j] = (unsigned char)(p8 & 0xffu);
        bar_lds();   // hbuf writes visible before next step's af reads
    }
}

// ---------------------------------------------------------------------------
// Emissions: 512 threads, 8 rows/block, w_cls staged in LDS once per block.
// R15: block 0 / tid 0 also zeroes out[0] (crf_k runs strictly after on the
// stream, so its atomicAdds see the zero). Saves the zero_out launch.
// ---------------------------------------------------------------------------
__global__ void __launch_bounds__(512) emis_k(
    const unsigned short* __restrict__ h_hist, const float* __restrict__ w_cls,
    const float* __restrict__ b_cls, float* __restrict__ em,
    float* __restrict__ out)
{
    if (blockIdx.x == 0 && threadIdx.x == 0) out[0] = 0.0f;

    __shared__ float wlds[L_ * 512];
    int tid = threadIdx.x;
    for (int i = tid; i < L_ * 512; i += 512) wlds[i] = w_cls[i];
    __syncthreads();

    int wid = tid >> 6, lane = tid & 63;
    size_t row = (size_t)blockIdx.x * 8 + wid;       // b*T + t
    const unsigned short* hf = h_hist + row * 256;
    const unsigned short* hb = h_hist + (size_t)64 * 512 * 256 + row * 256;
    ushort4 u0 = *(const ushort4*)(hf + 4 * lane);
    ushort4 u1 = *(const ushort4*)(hb + 4 * lane);
    float a0x = bf2f(u0.x), a0y = bf2f(u0.y), a0z = bf2f(u0.z), a0w = bf2f(u0.w);
    float a1x = bf2f(u1.x), a1y = bf2f(u1.y), a1z = bf2f(u1.z), a1w = bf2f(u1.w);
#pragma unroll
    for (int l = 0; l < L_; ++l) {
        const float* wr = &wlds[l * 512];
        float4 w0 = *(const float4*)(wr + 4 * lane);
        float4 w1 = *(const float4*)(wr + 256 + 4 * lane);
        float d = a0x * w0.x + a0y * w0.y + a0z * w0.z + a0w * w0.w
                + a1x * w1.x + a1y * w1.y + a1z * w1.z + a1w * w1.w;
#pragma unroll
        for (int off = 32; off; off >>= 1) d += __shfl_down(d, off);
        if (lane == 0) em[row * L_ + l] = d + b_cls[l];
    }
}

// ---------------------------------------------------------------------------
// CRF NLL (R11/R14 verbatim — verified)
// ---------------------------------------------------------------------------
__global__ void __launch_bounds__(64) crf_k(
    const float* __restrict__ em, const int* __restrict__ labels,
    const int* __restrict__ mask, const float* __restrict__ trans,
    const float* __restrict__ startv, const float* __restrict__ endv,
    float* __restrict__ out)
{
    int b = blockIdx.x, lane = threadIdx.x;
    const float* emb_ = em + (size_t)b * T_ * L_;
    const int* lab = labels + (size_t)b * T_;
    const int* msk = mask + (size_t)b * T_;
    __shared__ float alpha[L_];
    __shared__ float trs[81];
    for (int i = lane; i < 81; i += 64) trs[i] = trans[i];
    __syncthreads();

    float np = 0.0f;
    for (int t = 1 + lane; t < T_; t += 64)
        if (msk[t]) np += trs[lab[t - 1] * L_ + lab[t]] + emb_[(size_t)t * L_ + lab[t]];
    int mc = 0;
    for (int t = lane; t < T_; t += 64) mc += (msk[t] != 0);
#pragma unroll
    for (int off = 32; off; off >>= 1) {
        np += __shfl_down(np, off);
        mc += __shfl_down(mc, off);
    }
    float num = 0.0f;
    if (lane == 0) {
        int last = mc - 1;
        num = np + startv[lab[0]] + emb_[lab[0]] + endv[lab[last]];
    }

    int lane9 = (lane < L_) ? lane : 0;
    if (lane < L_) alpha[lane] = startv[lane] + emb_[lane];
    __syncthreads();

    float emt = emb_[L_ + lane9];    // prefetch t = 1
    int mk = msk[1];
    for (int t = 1; t < T_; ++t) {
        float em_c = emt;
        int mk_c = mk;
        if (t + 1 < T_) {
            emt = emb_[(size_t)(t + 1) * L_ + lane9];
            mk = msk[t + 1];
        }
        float na = 0.0f;
        if (lane < L_) {
            float m = -1e30f;
#pragma unroll
            for (int i = 0; i < L_; ++i) m = fmaxf(m, alpha[i] + trs[i * L_ + lane]);
            float s = 0.0f;
#pragma unroll
            for (int i = 0; i < L_; ++i) s += __expf(alpha[i] + trs[i * L_ + lane] - m);
            na = m + __logf(s) + em_c;
            if (!mk_c) na = alpha[lane];
        }
        __syncthreads();
        if (lane < L_) alpha[lane] = na;
        __syncthreads();
    }
    float v = (lane < L_) ? alpha[lane] + endv[lane] : -1e30f;
    float m = v;
#pragma unroll
    for (int off = 32; off; off >>= 1) m = fmaxf(m, __shfl_xor(m, off));
    float s = (lane < L_) ? __expf(v - m) : 0.0f;
#pragma unroll
    for (int off = 32; off; off >>= 1) s += __shfl_xor(s, off);
    if (lane == 0) {
        float logZ = m + __logf(s);
        atomicAdd(out, (logZ - num) / (float)B_);
    }
}

__global__ void ws_fail_k(float* out, float v) { out[0] = v; }

// ---------------------------------------------------------------------------
extern "C" void kernel_launch(void* const* d_in, const int* in_sizes, int n_in,
                              void* d_out, int out_size, void* d_ws, size_t ws_size,
                              hipStream_t stream)
{
    const int*   ids    = (const int*)  d_in[0];
    const int*   amask  = (const int*)  d_in[1];
    const int*   labels = (const int*)  d_in[2];
    const float* emb    = (const float*)d_in[3];
    const float* w_ih_f = (const float*)d_in[4];
    const float* w_hh_f = (const float*)d_in[5];
    const float* b_ih_f = (const float*)d_in[6];
    const float* b_hh_f = (const float*)d_in[7];
    const float* w_ih_b = (const float*)d_in[8];
    const float* w_hh_b = (const float*)d_in[9];
    const float* b_ih_b = (const float*)d_in[10];
    const float* b_hh_b = (const float*)d_in[11];
    const float* w_cls  = (const float*)d_in[12];
    const float* b_cls  = (const float*)d_in[13];
    const float* trans  = (const float*)d_in[14];
    const float* startv = (const float*)d_in[15];
    const float* endv   = (const float*)d_in[16];
    float* out = (float*)d_out;

    // workspace layout (16B-aligned chunks)
    size_t o_xg   = 0;                                    // bf16 xg: 128 MB
    size_t o_bias = o_xg + (size_t)NROW * NG * 2;
    size_t o_w8   = o_bias + 2048 * 4;                    // fp8 weights: 512 KB
    size_t o_embb = o_w8 + (size_t)2 * 1024 * 256;        // bf16 emb: 15.6 MB
    size_t o_wihb = o_embb + (size_t)32000 * 256 * 2;     // bf16 w_ih: 1 MB
    size_t o_hh   = o_wihb + (size_t)2048 * 256 * 2;      // h_hist: 32 MB
    size_t o_em   = o_hh + (size_t)2 * B_ * T_ * H_ * 2;
    size_t total  = o_em + (size_t)NROW * L_ * 4;

    if (ws_size < total) {
        ws_fail_k<<<1, 1, 0, stream>>>(out, -1.0e8f - (float)(ws_size >> 20));
        return;
    }

    unsigned short* xg       = (unsigned short*)((char*)d_ws + o_xg);
    float* bias              = (float*)((char*)d_ws + o_bias);
    unsigned int* w8         = (unsigned int*)((char*)d_ws + o_w8);
    unsigned short* embb     = (unsigned short*)((char*)d_ws + o_embb);
    unsigned short* wihb     = (unsigned short*)((char*)d_ws + o_wihb);
    unsigned short* h_hist   = (unsigned short*)((char*)d_ws + o_hh);
    float* em                = (float*)((char*)d_ws + o_em);

    prep_all<<<9032, 256, 0, stream>>>(emb, embb,
                                       w_ih_f, w_ih_b, w_hh_f, w_hh_b,
                                       b_ih_f, b_hh_f, b_ih_b, b_hh_b,
                                       wihb, w8, bias);
    xg_gemm_mfma<<<dim3(NROW / 128, NG / 128), 256, 0, stream>>>(
        embb, ids, wihb, bias, xg);
    lstm_fused<<<64, 512, 0, stream>>>(xg, (const unsigned long long*)w8, h_hist);
    emis_k<<<NROW / 8, 512, 0, stream>>>(h_hist, w_cls, b_cls, em, out);
    crf_k<<<B_, 64, 0, stream>>>(em, labels, amask, trans, startv, endv, out);
}